// Round 7
// baseline (150.782 us; speedup 1.0000x reference)
//
#include <hip/hip_runtime.h>

// BackgroundNoiseLayer, round 7: persistent fused kernel.
//   out[t, n*5+r] = sum_k spikes[t,k] * W[k, n*5+r],
//   W[k, c] = scatter-add over edges e (cols[e]=k, rows[e]=n) of weights[e]*tau[e,r]
//
// memset: zero bin counters
// K1: bucket edges by neuron-range (bin = row/16); 16 B records
//     {key, 5 x bf16 w*tau}; also builds bf16 spike table spb[256][128].
// K2 (persistent, 768 blocks = 3/CU): loop over bins. Per bin:
//     P0 re-zero prev bin's bf16 cells -> P1 LDS f32 atomic scatter ->
//     (prefetch next bin's records; stays in flight across raw barriers) ->
//     P2 touched-cell convert (5 reads + 5 swizzled bf16 writes per record) ->
//     P3 slice re-zero + MFMA GEMM + stores.
//     All barriers are raw lgkmcnt-only (phase deps are LDS-only), so global
//     prefetch loads are never drained by a barrier.
// Invariant: f32 slice and bf16 area are all-zero at each bin's P1/P2 entry
// (full zero once at start; touched cells re-zeroed by their own threads).

#define N_NEURONS 50000
#define N_BKG     100
#define N_SYN     5
#define N_EDGES   500000
#define SEQ_T     250
#define NCOL      (N_NEURONS * N_SYN)   // 250000
#define RPB       16                    // neurons per bin
#define NBINS     (N_NEURONS / RPB)     // 3125
#define CAP       512                   // record cap per bin (mean 160, +28 sigma)
#define KPAD      128                   // K padded 100 -> 128
#define CPAD      80                    // f32 slice leading dim
#define BCOLS     80                    // output cols per bin
#define GRID2     768                   // 3 blocks/CU x 256 CU
#define NOKEY     0xFFFFFFFFu

#define SLICE_BYTES 32000               // 100*80*4
#define BF_BYTES    20480               // 80 c * 128 k * 2 B
#define SMEM_BYTES  (SLICE_BYTES + BF_BYTES)   // 52480

// d_ws layout
#define WS_COUNT_OFF 0                  // NBINS u32
#define WS_SPB_OFF   32768              // 256*128 bf16 = 64 KB
#define WS_REC_OFF   131072             // NBINS*CAP*16 B = 25.6 MB

typedef __attribute__((ext_vector_type(8))) short bf16x8;
typedef __attribute__((ext_vector_type(4))) float f32x4;

// lgkm-only barrier: orders LDS ops across waves, leaves global loads in flight
#define LBAR() asm volatile("s_waitcnt lgkmcnt(0)\n\ts_barrier" ::: "memory")

__device__ inline unsigned short bf16_rne(float f) {
    unsigned u = __builtin_bit_cast(unsigned, f);
    u += 0x7FFFu + ((u >> 16) & 1u);
    return (unsigned short)(u >> 16);
}
__device__ inline float bf16_up(unsigned hw) {
    return __builtin_bit_cast(float, hw << 16);
}
// byte offset of (c,k) in the transposed swizzled bf16 area
__device__ inline int bf_addr(int c, int k) {
    return ((c << 8) + (k << 1)) ^ ((c & 7) << 4);
}

// K1: bucket-append edges (16 B records); first 32768 gids also build spb.
__global__ __launch_bounds__(256) void bucket_kernel(
        const float* __restrict__ weights,
        const float* __restrict__ tau,
        const int*   __restrict__ rows,
        const int*   __restrict__ cols,
        const float* __restrict__ spikes,
        unsigned* __restrict__ count,
        uint4* __restrict__ rec,
        unsigned short* __restrict__ spb) {
    int gid = blockIdx.x * 256 + threadIdx.x;
    if (gid < 256 * KPAD) {                      // spb[t][k], 256 x 128
        int t = gid >> 7, k = gid & 127;
        unsigned short v = 0;
        if (t < SEQ_T && k < N_BKG) {
            float s = spikes[t * N_BKG + k];     // 0/1 -> bf16 exact
            v = bf16_rne(s);
        }
        spb[gid] = v;
    }
    if (gid >= N_EDGES) return;
    int row = rows[gid];
    int col = cols[gid];
    float w = weights[gid];
    const float* tp = tau + (size_t)gid * N_SYN;
    int bin = row >> 4;
    unsigned slot = atomicAdd(&count[bin], 1u);
    if (slot >= CAP) return;                     // statistically impossible
    uint4 r;
    r.x = ((unsigned)col << 4) | (unsigned)(row & 15);
    r.y = (unsigned)bf16_rne(w * tp[0]) | ((unsigned)bf16_rne(w * tp[1]) << 16);
    r.z = (unsigned)bf16_rne(w * tp[2]) | ((unsigned)bf16_rne(w * tp[3]) << 16);
    r.w = (unsigned)bf16_rne(w * tp[4]);
    rec[(size_t)bin * CAP + slot] = r;
}

// K2: persistent fused scatter + convert + MFMA GEMM.
// Swapped operands: A = W bf16 frag (M = c), B = spike frag (N = t).
// D: col = t = l&15, row = c = (l>>4)*4+reg -> float4 stores along c.
__global__ __launch_bounds__(256, 3) void fused_kernel(
        const unsigned* __restrict__ count,
        const uint4* __restrict__ rec,
        const unsigned short* __restrict__ spb,
        float* __restrict__ out) {
    __shared__ __align__(16) char smem[SMEM_BYTES];
    float* slice = (float*)smem;                 // f32 [100][80]
    char*  bfa   = smem + SLICE_BYTES;           // bf16 [80][128] swizzled

    const int tid = threadIdx.x;
    const int l  = tid & 63;
    const int wv = tid >> 6;
    const int lc = l & 15;
    const int lq = l >> 4;

    // ---- full zero of both areas (once) ----
    {
        f32x4* s4 = (f32x4*)smem;
        f32x4 z = (f32x4){0.f, 0.f, 0.f, 0.f};
        for (int i = tid; i < SMEM_BYTES / 16; i += 256) s4[i] = z;
    }

    int bin = blockIdx.x;
    // ---- prefetch first bin ----
    unsigned cnt = count[bin];
    if (cnt > CAP) cnt = CAP;
    uint4 ra = rec[(size_t)bin * CAP + tid];
    uint4 rb = make_uint4(0, 0, 0, 0);
    if (tid + 256u < cnt) rb = rec[(size_t)bin * CAP + tid + 256];

    unsigned okeya = NOKEY, okeyb = NOKEY;

    while (bin < NBINS) {
        LBAR();                                  // zero/P0 visible to P1
        bool havea = (unsigned)tid < cnt;
        bool haveb = (unsigned)tid + 256u < cnt;

        // ---- P1: LDS f32 atomic scatter ----
        if (havea) {
            float* base = &slice[(ra.x >> 4) * CPAD + (ra.x & 15u) * N_SYN];
            atomicAdd(base + 0, bf16_up(ra.y & 0xFFFFu));
            atomicAdd(base + 1, bf16_up(ra.y >> 16));
            atomicAdd(base + 2, bf16_up(ra.z & 0xFFFFu));
            atomicAdd(base + 3, bf16_up(ra.z >> 16));
            atomicAdd(base + 4, bf16_up(ra.w & 0xFFFFu));
        }
        if (haveb) {
            float* base = &slice[(rb.x >> 4) * CPAD + (rb.x & 15u) * N_SYN];
            atomicAdd(base + 0, bf16_up(rb.y & 0xFFFFu));
            atomicAdd(base + 1, bf16_up(rb.y >> 16));
            atomicAdd(base + 2, bf16_up(rb.z & 0xFFFFu));
            atomicAdd(base + 3, bf16_up(rb.w & 0xFFFFu));
        }
        LBAR();                                  // atomics done before P2 reads

        // ---- prefetch next bin (stays in flight across lgkm barriers) ----
        int binN = bin + GRID2;
        unsigned cntN = 0;
        uint4 raN = make_uint4(0, 0, 0, 0);
        uint4 rbN = make_uint4(0, 0, 0, 0);
        if (binN < NBINS) {
            raN  = rec[(size_t)binN * CAP + tid];
            cntN = count[binN];
            if (cntN > CAP) cntN = CAP;
            if (tid + 256u < cntN) rbN = rec[(size_t)binN * CAP + tid + 256];
        }

        // ---- P2: touched-cell convert (read final f32, write swizzled bf16) --
        if (havea) {
            int k = (int)(ra.x >> 4), noff = (int)(ra.x & 15u);
            const float* cell = &slice[k * CPAD + noff * N_SYN];
#pragma unroll
            for (int r = 0; r < N_SYN; ++r) {
                int c = noff * N_SYN + r;
                *(unsigned short*)(bfa + bf_addr(c, k)) = bf16_rne(cell[r]);
            }
        }
        if (haveb) {
            int k = (int)(rb.x >> 4), noff = (int)(rb.x & 15u);
            const float* cell = &slice[k * CPAD + noff * N_SYN];
#pragma unroll
            for (int r = 0; r < N_SYN; ++r) {
                int c = noff * N_SYN + r;
                *(unsigned short*)(bfa + bf_addr(c, k)) = bf16_rne(cell[r]);
            }
        }
        LBAR();                                  // bf16 writes visible to GEMM

        // ---- P3: slice re-zero (restore invariant) + MFMA GEMM + stores ----
        if (havea) {
            float* cell = &slice[(ra.x >> 4) * CPAD + (ra.x & 15u) * N_SYN];
#pragma unroll
            for (int r = 0; r < N_SYN; ++r) cell[r] = 0.f;
        }
        if (haveb) {
            float* cell = &slice[(rb.x >> 4) * CPAD + (rb.x & 15u) * N_SYN];
#pragma unroll
            for (int r = 0; r < N_SYN; ++r) cell[r] = 0.f;
        }

        f32x4 acc[5][4];
#pragma unroll
        for (int m = 0; m < 5; ++m)
#pragma unroll
            for (int n = 0; n < 4; ++n)
                acc[m][n] = (f32x4){0.f, 0.f, 0.f, 0.f};

#pragma unroll
        for (int kk = 0; kk < 4; ++kk) {
            bf16x8 bs[4];
#pragma unroll
            for (int n = 0; n < 4; ++n) {
                int t = (wv * 4 + n) * 16 + lc;          // < 256, pad rows 0
                bs[n] = *(const bf16x8*)(spb + (size_t)t * KPAD + kk * 32 + lq * 8);
            }
#pragma unroll
            for (int m = 0; m < 5; ++m) {
                int c = m * 16 + lc;
                int bor = ((c << 8) + (kk << 6) + (lq << 4)) ^ ((c & 7) << 4);
                bf16x8 ah = *(const bf16x8*)(bfa + bor);
#pragma unroll
                for (int n = 0; n < 4; ++n)
                    acc[m][n] = __builtin_amdgcn_mfma_f32_16x16x32_bf16(
                                    ah, bs[n], acc[m][n], 0, 0, 0);
            }
        }

        const int cb = bin * BCOLS;
#pragma unroll
        for (int m = 0; m < 5; ++m) {
            int c = cb + m * 16 + lq * 4;
#pragma unroll
            for (int n = 0; n < 4; ++n) {
                int t = (wv * 4 + n) * 16 + lc;
                if (t < SEQ_T)
                    *(f32x4*)(out + (size_t)t * NCOL + c) = acc[m][n];
            }
        }

        // ---- rotate to next bin ----
        okeya = havea ? ra.x : NOKEY;
        okeyb = haveb ? rb.x : NOKEY;
        cnt = cntN; ra = raN; rb = rbN; bin = binN;

        LBAR();                                  // GEMM bf reads done before P0

        // ---- P0 (for next bin): re-zero previous bin's bf16 cells ----
        if (bin < NBINS) {
            if (okeya != NOKEY) {
                int k = (int)(okeya >> 4), noff = (int)(okeya & 15u);
#pragma unroll
                for (int r = 0; r < N_SYN; ++r)
                    *(unsigned short*)(bfa + bf_addr(noff * N_SYN + r, k)) = 0;
            }
            if (okeyb != NOKEY) {
                int k = (int)(okeyb >> 4), noff = (int)(okeyb & 15u);
#pragma unroll
                for (int r = 0; r < N_SYN; ++r)
                    *(unsigned short*)(bfa + bf_addr(noff * N_SYN + r, k)) = 0;
            }
        }
    }
}

extern "C" void kernel_launch(void* const* d_in, const int* in_sizes, int n_in,
                              void* d_out, int out_size, void* d_ws, size_t ws_size,
                              hipStream_t stream) {
    const float* weights = (const float*)d_in[0];
    const float* tau     = (const float*)d_in[1];
    const float* spikes  = (const float*)d_in[2];
    const int*   rows    = (const int*)d_in[3];
    const int*   cols    = (const int*)d_in[4];
    float* out = (float*)d_out;

    char* ws = (char*)d_ws;
    unsigned*       count = (unsigned*)(ws + WS_COUNT_OFF);
    unsigned short* spb   = (unsigned short*)(ws + WS_SPB_OFF);
    uint4*          rec   = (uint4*)(ws + WS_REC_OFF);

    hipMemsetAsync(count, 0, NBINS * sizeof(unsigned), stream);

    int eblocks = (N_EDGES + 255) / 256;
    bucket_kernel<<<eblocks, 256, 0, stream>>>(weights, tau, rows, cols, spikes,
                                               count, rec, spb);

    fused_kernel<<<GRID2, 256, 0, stream>>>(count, rec, spb, out);
}